// Round 9
// baseline (1139.688 us; speedup 1.0000x reference)
//
#include <hip/hip_runtime.h>
#include <hip/hip_fp16.h>

// HyperScatteringModule: V=65536, E=16384, NNZ=1048576, F=128
#define FEAT 128

// ---------------- fp16 helpers ----------------

__device__ inline float hlo(unsigned u) {
    unsigned short s = (unsigned short)(u & 0xFFFFu);
    __half h = *(__half*)&s;
    return __half2float(h);
}
__device__ inline float hhi(unsigned u) {
    unsigned short s = (unsigned short)(u >> 16);
    __half h = *(__half*)&s;
    return __half2float(h);
}
__device__ inline unsigned hpack(float a, float b) {
    __half ha = __float2half_rn(a), hb = __float2half_rn(b);
    unsigned short ua = *(unsigned short*)&ha, ub = *(unsigned short*)&hb;
    return (unsigned)ua | ((unsigned)ub << 16);
}

// ---------------- fp8 e4m3 helpers (byte b of a row = feat b) ----------------
#if __has_builtin(__builtin_amdgcn_cvt_pk_f32_fp8) && __has_builtin(__builtin_amdgcn_cvt_pk_fp8_f32)
typedef float floatx2 __attribute__((ext_vector_type(2)));
__device__ inline void fp8x2lo(unsigned u, float& a, float& b) {
    floatx2 r = __builtin_amdgcn_cvt_pk_f32_fp8((int)u, false);
    a = r.x; b = r.y;
}
__device__ inline void fp8x2hi(unsigned u, float& a, float& b) {
    floatx2 r = __builtin_amdgcn_cvt_pk_f32_fp8((int)u, true);
    a = r.x; b = r.y;
}
__device__ inline unsigned fp8x4(float a, float b, float c, float d) {
    int w = __builtin_amdgcn_cvt_pk_fp8_f32(a, b, 0, false);
    w = __builtin_amdgcn_cvt_pk_fp8_f32(c, d, w, true);
    return (unsigned)w;
}
#else
// Fallback bit-twiddle codec for OCP e4m3fn
__device__ inline float fp8_dec1(unsigned u) {
    unsigned s = (u >> 7) & 1u, e = (u >> 3) & 15u, m = u & 7u;
    float v;
    if (e != 0) {
        unsigned bits = (s << 31) | ((e + 120u) << 23) | (m << 20);
        v = __uint_as_float(bits);
    } else {
        v = (float)m * 0.001953125f;
        if (s) v = -v;
    }
    return v;
}
__device__ inline void fp8x2lo(unsigned u, float& a, float& b) {
    a = fp8_dec1(u & 0xFFu);
    b = fp8_dec1((u >> 8) & 0xFFu);
}
__device__ inline void fp8x2hi(unsigned u, float& a, float& b) {
    a = fp8_dec1((u >> 16) & 0xFFu);
    b = fp8_dec1((u >> 24) & 0xFFu);
}
__device__ inline unsigned fp8_enc1(float x) {
    float ax = fabsf(x);
    unsigned s = (__float_as_uint(x) >> 31) << 7;
    if (ax >= 448.f) return s | 0x7Eu;
    if (ax < 0.0009765625f) return s;
    if (ax < 0.015625f) {
        unsigned m = (unsigned)__builtin_rintf(ax * 512.f);
        if (m > 7u) m = 7u;
        return s | m;
    }
    unsigned bits = __float_as_uint(ax);
    int e32 = (int)((bits >> 23) & 255u) - 127;
    unsigned mant = bits & 0x7FFFFFu;
    unsigned m3 = mant >> 20;
    unsigned rem = mant & 0xFFFFFu;
    if (rem > 0x80000u || (rem == 0x80000u && (m3 & 1u))) {
        m3++;
        if (m3 == 8u) { m3 = 0; e32++; }
    }
    if (e32 > 8) return s | 0x7Eu;
    return s | ((unsigned)(e32 + 7) << 3) | m3;
}
__device__ inline unsigned fp8x4(float a, float b, float c, float d) {
    return fp8_enc1(a) | (fp8_enc1(b) << 8) | (fp8_enc1(c) << 16) | (fp8_enc1(d) << 24);
}
#endif

// ---------------- CSR build ----------------

__global__ void count_deg(const int* __restrict__ vids, const int* __restrict__ eids,
                          int* __restrict__ deg_v, int* __restrict__ deg_e, int nnz) {
    int n = blockIdx.x * blockDim.x + threadIdx.x;
    if (n < nnz) {
        atomicAdd(&deg_v[vids[n]], 1);
        atomicAdd(&deg_e[eids[n]], 1);
    }
}

// Exclusive scan over CHUNK-padded degrees; off/cur = padded offsets, inv = 1/true_deg.
template <int N, int T, int CHUNK>
__global__ __launch_bounds__(T) void scan_pad(const int* __restrict__ deg,
                                              int* __restrict__ off,
                                              int* __restrict__ cur,
                                              float* __restrict__ inv) {
    __shared__ int partial[T];
    const int per = N / T;
    int tid = threadIdx.x;
    int base = tid * per;
    int dloc[per];
    int s = 0;
#pragma unroll
    for (int i = 0; i < per / 4; ++i) {
        int4 d4 = *(const int4*)(deg + base + 4 * i);
        dloc[4 * i] = d4.x; dloc[4 * i + 1] = d4.y;
        dloc[4 * i + 2] = d4.z; dloc[4 * i + 3] = d4.w;
        s += ((d4.x + CHUNK - 1) & ~(CHUNK - 1)) + ((d4.y + CHUNK - 1) & ~(CHUNK - 1)) +
             ((d4.z + CHUNK - 1) & ~(CHUNK - 1)) + ((d4.w + CHUNK - 1) & ~(CHUNK - 1));
    }
    partial[tid] = s;
    __syncthreads();
    for (int d = 1; d < T; d <<= 1) {
        int add = (tid >= d) ? partial[tid - d] : 0;
        __syncthreads();
        partial[tid] += add;
        __syncthreads();
    }
    int run = (tid > 0) ? partial[tid - 1] : 0;
#pragma unroll
    for (int i = 0; i < per / 4; ++i) {
        int o[4];
        float iv[4];
#pragma unroll
        for (int j = 0; j < 4; ++j) {
            int d = dloc[4 * i + j];
            o[j] = run;
            iv[j] = (d > 0) ? (1.0f / (float)d) : 0.0f;
            run += (d + CHUNK - 1) & ~(CHUNK - 1);
        }
        *(int4*)(off + base + 4 * i) = make_int4(o[0], o[1], o[2], o[3]);
        *(int4*)(cur + base + 4 * i) = make_int4(o[0], o[1], o[2], o[3]);
        *(float4*)(inv + base + 4 * i) = make_float4(iv[0], iv[1], iv[2], iv[3]);
    }
    if (tid == T - 1) off[N] = run;
}

// Fill padded slots with dummy row indices; zero the dummy rows of xs8/es8.
__global__ void init_pad(int* __restrict__ nbrE, int nE, int dummyE,
                         int* __restrict__ nbrV, int nV, int dummyV,
                         unsigned* __restrict__ x8zero, unsigned* __restrict__ e8zero) {
    int i = blockIdx.x * 256 + threadIdx.x;
    if (i < nE) nbrE[i] = dummyE;
    if (i < nV) nbrV[i] = dummyV;
    if (i < 32) { x8zero[i] = 0u; e8zero[i] = 0u; }  // 128B fp8 dummy rows
}

__global__ void fill_csr(const int* __restrict__ vids, const int* __restrict__ eids,
                         int* __restrict__ cur_v, int* __restrict__ cur_e,
                         int* __restrict__ v_nbr_e, int* __restrict__ e_nbr_v, int nnz) {
    int n = blockIdx.x * blockDim.x + threadIdx.x;
    if (n < nnz) {
        int v = vids[n], e = eids[n];
        int p = atomicAdd(&cur_e[e], 1);
        e_nbr_v[p] = v;
        int q = atomicAdd(&cur_v[v], 1);
        v_nbr_e[q] = e;
    }
}

// ---------------- prescale: xs8[v] = fp8(X[v] * inv_v), 4 feats/thread ----------------
__global__ __launch_bounds__(256) void prescale(const float* __restrict__ X,
                                                const float* __restrict__ inv_v,
                                                unsigned* __restrict__ xs8) {
    int tid = blockIdx.x * 256 + threadIdx.x;  // over V*32 dwords
    int v = tid >> 5, d = tid & 31;
    float sc = inv_v[v];
    float4 x = *(const float4*)(X + (size_t)v * FEAT + 4 * d);
    xs8[(size_t)v * 32 + d] = fp8x4(x.x * sc, x.y * sc, x.z * sc, x.w * sc);
}

// ---------------- v2e gather: 8 rows per dwordx4 instruction ----------------
// Wave per edge-segment (CHUNK=8 padded, dummy row = zeros). Lane-group g=lane>>3
// owns one of 8 neighbor rows; lane reads 16B (16 fp8 feats) at piece q=lane&7.
// fp32 accumulate (16/lane); 3-level xor-shfl reduce; lanes 0..7 store 128B row.
__global__ __launch_bounds__(256) void gather_v2e(const char* __restrict__ xs8b,
                                                  const int* __restrict__ offs,
                                                  const int* __restrict__ nbr,
                                                  const float* __restrict__ inv_e,
                                                  char* __restrict__ es8b, int nseg) {
    int seg = __builtin_amdgcn_readfirstlane(blockIdx.x * 4 + (threadIdx.x >> 6));
    if (seg >= nseg) return;
    int lane = threadIdx.x & 63;
    int q = lane & 7, g = lane >> 3;
    int p = offs[seg], pend = offs[seg + 1];
    float acc[16];
#pragma unroll
    for (int j = 0; j < 16; ++j) acc[j] = 0.f;
    for (; p < pend; p += 8) {
        int4 c0 = *(const int4*)(nbr + p);
        int4 c1 = *(const int4*)(nbr + p + 4);
        int i0 = (g & 2) ? ((g & 1) ? c0.w : c0.z) : ((g & 1) ? c0.y : c0.x);
        int i1 = (g & 2) ? ((g & 1) ? c1.w : c1.z) : ((g & 1) ? c1.y : c1.x);
        int idx = (g & 4) ? i1 : i0;
        uint4 r = *(const uint4*)(xs8b + (((size_t)(unsigned)idx) << 7) + (q << 4));
        float a, b;
        fp8x2lo(r.x, a, b); acc[0] += a;  acc[1] += b;
        fp8x2hi(r.x, a, b); acc[2] += a;  acc[3] += b;
        fp8x2lo(r.y, a, b); acc[4] += a;  acc[5] += b;
        fp8x2hi(r.y, a, b); acc[6] += a;  acc[7] += b;
        fp8x2lo(r.z, a, b); acc[8] += a;  acc[9] += b;
        fp8x2hi(r.z, a, b); acc[10] += a; acc[11] += b;
        fp8x2lo(r.w, a, b); acc[12] += a; acc[13] += b;
        fp8x2hi(r.w, a, b); acc[14] += a; acc[15] += b;
    }
#pragma unroll
    for (int j = 0; j < 16; ++j) acc[j] += __shfl_xor(acc[j], 8, 64);
#pragma unroll
    for (int j = 0; j < 16; ++j) acc[j] += __shfl_xor(acc[j], 16, 64);
#pragma unroll
    for (int j = 0; j < 16; ++j) acc[j] += __shfl_xor(acc[j], 32, 64);
    if (lane < 8) {
        float sc = inv_e[seg];
        uint4 o;
        o.x = fp8x4(acc[0] * sc, acc[1] * sc, acc[2] * sc, acc[3] * sc);
        o.y = fp8x4(acc[4] * sc, acc[5] * sc, acc[6] * sc, acc[7] * sc);
        o.z = fp8x4(acc[8] * sc, acc[9] * sc, acc[10] * sc, acc[11] * sc);
        o.w = fp8x4(acc[12] * sc, acc[13] * sc, acc[14] * sc, acc[15] * sc);
        *(uint4*)(es8b + (((size_t)seg) << 7) + (lane << 4)) = o;
    }
}

// ---------------- e2v gather: 4 rows per dwordx2 instruction ----------------
// Wave handles 4 vertex-segments (CHUNK=4 padded). Lane-group g=lane>>4 owns one
// of 4 neighbor rows; lane reads 8B (8 fp8 feats) at piece q=lane&15.
// fp32 accumulate (8/lane); 2-level reduce; lanes 0..15 store fp8 row + fp16 ckpt.
__global__ __launch_bounds__(256) void gather_e2v(const char* __restrict__ es8b,
                                                  const int* __restrict__ offs,
                                                  const int* __restrict__ nbr,
                                                  const float* __restrict__ inv_v,
                                                  char* __restrict__ xs8b,
                                                  unsigned* __restrict__ ckpt, int nseg) {
    int wv = __builtin_amdgcn_readfirstlane(blockIdx.x * 4 + (threadIdx.x >> 6));
    int lane = threadIdx.x & 63;
    int q = lane & 15, g = lane >> 4;
    int seg0 = wv * 4;
    if (seg0 >= nseg) return;
    int p = offs[seg0];
#pragma unroll
    for (int i = 0; i < 4; ++i) {
        int s = seg0 + i;
        int pend = offs[s + 1];
        float acc[8];
#pragma unroll
        for (int j = 0; j < 8; ++j) acc[j] = 0.f;
        for (; p < pend; p += 4) {
            int4 c = *(const int4*)(nbr + p);
            int idx = (g & 2) ? ((g & 1) ? c.w : c.z) : ((g & 1) ? c.y : c.x);
            uint2 r = *(const uint2*)(es8b + (((size_t)(unsigned)idx) << 7) + (q << 3));
            float a, b;
            fp8x2lo(r.x, a, b); acc[0] += a; acc[1] += b;
            fp8x2hi(r.x, a, b); acc[2] += a; acc[3] += b;
            fp8x2lo(r.y, a, b); acc[4] += a; acc[5] += b;
            fp8x2hi(r.y, a, b); acc[6] += a; acc[7] += b;
        }
#pragma unroll
        for (int j = 0; j < 8; ++j) acc[j] += __shfl_xor(acc[j], 16, 64);
#pragma unroll
        for (int j = 0; j < 8; ++j) acc[j] += __shfl_xor(acc[j], 32, 64);
        if (lane < 16) {
            float sc = inv_v[s];
            float f0 = acc[0] * sc, f1 = acc[1] * sc, f2 = acc[2] * sc, f3 = acc[3] * sc;
            float f4 = acc[4] * sc, f5 = acc[5] * sc, f6 = acc[6] * sc, f7 = acc[7] * sc;
            uint2 o;
            o.x = fp8x4(f0, f1, f2, f3);
            o.y = fp8x4(f4, f5, f6, f7);
            *(uint2*)(xs8b + (((size_t)s) << 7) + (lane << 3)) = o;
            if (ckpt) {
                uint4 h;
                h.x = hpack(f0, f1);
                h.y = hpack(f2, f3);
                h.z = hpack(f4, f5);
                h.w = hpack(f6, f7);
                *(uint4*)(ckpt + (size_t)s * 1536 + lane * 4) = h;
            }
        }
    }
}

// ---------------- final wavelet combine + relu split ----------------
// Checkpoints: fp16(inv_v*L) at out dwords v*1536 + slot*256 + [0,64).
// Recover L = ckpt * deg_v. 256 threads = 8 vertices, 4 feats/thread.
__global__ __launch_bounds__(256) void wavelet_out(const float* __restrict__ X,
                                                   const int* __restrict__ deg_v,
                                                   float* __restrict__ out) {
    int tid = blockIdx.x * 256 + threadIdx.x;
    int v = tid >> 5;
    int f4 = (tid & 31) * 4;
    float* row = out + (size_t)v * 1536;
    const unsigned* rowu = (const unsigned*)row;
    float degf = (float)deg_v[v];
    float4 L0v = *(const float4*)(X + (size_t)v * FEAT + f4);
    float l0[4] = {L0v.x, L0v.y, L0v.z, L0v.w};
    float L[5][4];
#pragma unroll
    for (int s = 0; s < 5; ++s) {
        unsigned d0 = rowu[(s + 1) * 256 + (f4 >> 1)];
        unsigned d1 = rowu[(s + 1) * 256 + (f4 >> 1) + 1];
        L[s][0] = hlo(d0) * degf;
        L[s][1] = hhi(d0) * degf;
        L[s][2] = hlo(d1) * degf;
        L[s][3] = hhi(d1) * degf;
    }
    float wv[6][4];
#pragma unroll
    for (int j = 0; j < 4; ++j) {
        wv[0][j] = l0[j] - L[0][j];
        wv[1][j] = L[0][j] - L[1][j];
        wv[2][j] = L[1][j] - L[2][j];
        wv[3][j] = L[2][j] - L[3][j];
        wv[4][j] = L[3][j] - L[4][j];
        wv[5][j] = L[4][j];
    }
    __syncthreads();
#pragma unroll
    for (int r = 0; r < 6; ++r) {
        float4 pp, mm;
        pp.x = fmaxf(wv[r][0], 0.f); mm.x = fmaxf(-wv[r][0], 0.f);
        pp.y = fmaxf(wv[r][1], 0.f); mm.y = fmaxf(-wv[r][1], 0.f);
        pp.z = fmaxf(wv[r][2], 0.f); mm.z = fmaxf(-wv[r][2], 0.f);
        pp.w = fmaxf(wv[r][3], 0.f); mm.w = fmaxf(-wv[r][3], 0.f);
        *(float4*)(row + r * 256 + f4) = pp;
        *(float4*)(row + r * 256 + 128 + f4) = mm;
    }
}

// ---------------- launch ----------------

extern "C" void kernel_launch(void* const* d_in, const int* in_sizes, int n_in,
                              void* d_out, int out_size, void* d_ws, size_t ws_size,
                              hipStream_t stream) {
    const float* X = (const float*)d_in[0];
    const int* vids = (const int*)d_in[1];
    const int* eids = (const int*)d_in[2];
    const int NNZ = in_sizes[1];       // 1048576
    const int V = in_sizes[0] / FEAT;  // 65536
    const int E = 16384;               // num_e
    float* out = (float*)d_out;

    const int NBRE_CAP = NNZ + E * 8;  // edge lists, CHUNK=8 padding
    const int NBRV_CAP = NNZ + V * 4;  // vertex lists, CHUNK=4 padding

    char* w = (char*)d_ws;
    size_t o = 0;
    auto take = [&](size_t bytes) {
        void* p = (void*)(w + o);
        o = (o + bytes + 255) & ~(size_t)255;
        return p;
    };
    int* deg_v = (int*)take((size_t)(V + E) * 4);  // deg_v, deg_e contiguous
    int* deg_e = deg_v + V;
    int* off_e = (int*)take((size_t)(E + 1) * 4);
    int* off_v = (int*)take((size_t)(V + 1) * 4);
    int* cur_e = (int*)take((size_t)E * 4);
    int* cur_v = (int*)take((size_t)V * 4);
    float* inv_e = (float*)take((size_t)E * 4);
    float* inv_v = (float*)take((size_t)V * 4);
    int* e_nbr_v = (int*)take((size_t)NBRE_CAP * 4);            // edge segs -> vertex rows
    int* v_nbr_e = (int*)take((size_t)NBRV_CAP * 4);            // vertex segs -> edge rows
    unsigned* xs8 = (unsigned*)take((size_t)(V + 1) * 32 * 4);  // fp8 [V+1][128] = 8.4MB
    unsigned* es8 = (unsigned*)take((size_t)(E + 1) * 32 * 4);  // fp8 [E+1][128] = 2.1MB
    (void)ws_size;
    (void)n_in;
    (void)out_size;

    // 1) degrees
    hipMemsetAsync(deg_v, 0, (size_t)(V + E) * 4, stream);
    count_deg<<<(NNZ + 255) / 256, 256, 0, stream>>>(vids, eids, deg_v, deg_e, NNZ);

    // 2) padded offsets + cursors + 1/true-degree
    scan_pad<16384, 1024, 8><<<1, 1024, 0, stream>>>(deg_e, off_e, cur_e, inv_e);
    scan_pad<65536, 1024, 4><<<1, 1024, 0, stream>>>(deg_v, off_v, cur_v, inv_v);

    // 3) dummy-fill padded lists (dummy -> zero row), zero dummy rows
    {
        int mx = NBRV_CAP > NBRE_CAP ? NBRV_CAP : NBRE_CAP;
        init_pad<<<(mx + 255) / 256, 256, 0, stream>>>(e_nbr_v, NBRE_CAP, V,
                                                       v_nbr_e, NBRV_CAP, E,
                                                       xs8 + (size_t)V * 32,
                                                       es8 + (size_t)E * 32);
    }

    // 4) adjacency lists
    fill_csr<<<(NNZ + 255) / 256, 256, 0, stream>>>(vids, eids, cur_v, cur_e,
                                                    v_nbr_e, e_nbr_v, NNZ);

    // 5) xs8 = fp8(X * inv_v)
    prescale<<<V * 32 / 256, 256, 0, stream>>>(X, inv_v, xs8);

    // 6) 16 diffusion steps; checkpoints k in {1,2,4,8,16} also write packed
    //    fp16 scaled level into out[v, slot, dwords 0:64] (recovered by *deg_v).
    for (int k = 1; k <= 16; ++k) {
        gather_v2e<<<E / 4, 256, 0, stream>>>((const char*)xs8, off_e, e_nbr_v,
                                              inv_e, (char*)es8, E);
        unsigned* ck = nullptr;
        if (k == 1) ck = (unsigned*)out + 1 * 256;
        else if (k == 2) ck = (unsigned*)out + 2 * 256;
        else if (k == 4) ck = (unsigned*)out + 3 * 256;
        else if (k == 8) ck = (unsigned*)out + 4 * 256;
        else if (k == 16) ck = (unsigned*)out + 5 * 256;
        gather_e2v<<<V / 16, 256, 0, stream>>>((const char*)es8, off_v, v_nbr_e,
                                               inv_v, (char*)xs8, ck, V);
    }

    // 7) wavelet combine + relu split, in place over out
    wavelet_out<<<V * 32 / 256, 256, 0, stream>>>(X, deg_v, out);
}